// Round 4
// baseline (3277.585 us; speedup 1.0000x reference)
//
#include <hip/hip_runtime.h>

#define H 51

__device__ __forceinline__ float rl_(float v, int lane) {
    return __builtin_bit_cast(float, __builtin_amdgcn_readlane(__builtin_bit_cast(int, v), lane));
}
template<int CTRL>
__device__ __forceinline__ float qb_(float v) {   // quad_perm broadcast (DPP, VALU pipe)
    return __builtin_bit_cast(float, __builtin_amdgcn_update_dpp(
        0, __builtin_bit_cast(int, v), CTRL, 0xf, 0xf, true));
}

// act = A * rcp(1 + exp2(m2*x)) + B   (sigmoid: m2=-log2e,A=1,B=0 ; tanh: m2=2log2e,A=-2,B=1)
__device__ __forceinline__ float act_(float x, float m2, float A, float B) {
    const float e = __builtin_amdgcn_exp2f(m2 * x);
    const float r = __builtin_amdgcn_rcpf(1.f + e);
    return fmaf(A, r, B);
}
__device__ __forceinline__ float tanh_(float c) {
    const float e = __builtin_amdgcn_exp2f(2.885390082f * c);
    const float r = __builtin_amdgcn_rcpf(1.f + e);
    return fmaf(-2.f, r, 1.f);
}

// ---- apply M(k) for k = 0..50 ----
#define FOR51(M) \
 M(0) M(1) M(2) M(3) M(4) M(5) M(6) M(7) M(8) M(9) \
 M(10) M(11) M(12) M(13) M(14) M(15) M(16) M(17) M(18) M(19) \
 M(20) M(21) M(22) M(23) M(24) M(25) M(26) M(27) M(28) M(29) \
 M(30) M(31) M(32) M(33) M(34) M(35) M(36) M(37) M(38) M(39) \
 M(40) M(41) M(42) M(43) M(44) M(45) M(46) M(47) M(48) M(49) M(50)

// ---- apply M(k, k%4) for k = 0..50 (round-robin accumulators, same order as round 3) ----
#define FOR51_RR(M) \
 M(0,0) M(1,1) M(2,2) M(3,3) M(4,0) M(5,1) M(6,2) M(7,3) \
 M(8,0) M(9,1) M(10,2) M(11,3) M(12,0) M(13,1) M(14,2) M(15,3) \
 M(16,0) M(17,1) M(18,2) M(19,3) M(20,0) M(21,1) M(22,2) M(23,3) \
 M(24,0) M(25,1) M(26,2) M(27,3) M(28,0) M(29,1) M(30,2) M(31,3) \
 M(32,0) M(33,1) M(34,2) M(35,3) M(36,0) M(37,1) M(38,2) M(39,3) \
 M(40,0) M(41,1) M(42,2) M(43,3) M(44,0) M(45,1) M(46,2) M(47,3) \
 M(48,0) M(49,1) M(50,2)

__global__ __launch_bounds__(256, 1)
void lstm_seq_kernel(const float* __restrict__ x,
                     const float* __restrict__ Wih1, const float* __restrict__ Whh1,
                     const float* __restrict__ bih1, const float* __restrict__ bhh1,
                     const float* __restrict__ Wih2, const float* __restrict__ Whh2,
                     const float* __restrict__ bih2, const float* __restrict__ bhh2,
                     const float* __restrict__ fcw, const float* __restrict__ fcb,
                     float* __restrict__ out, int T, int future)
{
    const int b   = blockIdx.x;
    const int tid = threadIdx.x;
    const int l   = tid & 63;          // lane
    const int w   = tid >> 6;          // wave 0..3
    const int uq  = l >> 2;            // unit-within-wave 0..15 (13 valid)
    const int g   = l & 3;             // gate 0:i 1:f 2:g 3:o
    const int u   = 13 * w + uq;       // unit 0..50
    const bool act_lane = (uq < 13) && (u < H);
    const bool g0lane   = act_lane && (g == 0);

    extern __shared__ float xld[];              // [T] this batch row of x
    __shared__ float h1s[2][64];                // double-buffered h1 (pad zeros)
    __shared__ float h2s[2][64];
    __shared__ __align__(16) float fcp[4];      // per-wave fc partial sums

    for (int i = tid; i < T; i += 256) xld[i] = x[(size_t)b * T + i];
    if (tid < 64) { h1s[0][tid] = 0.f; h1s[1][tid] = 0.f;
                    h2s[0][tid] = 0.f; h2s[1][tid] = 0.f; }
    if (tid < 4) fcp[tid] = 0.f;

    const int row = act_lane ? (g * H + u) : 0;
    const float wx1   = act_lane ? Wih1[row] : 0.f;
    const float bias1 = act_lane ? (bih1[row] + bhh1[row]) : 0.f;
    const float bias2 = act_lane ? (bih2[row] + bhh2[row]) : 0.f;
    const float fcu   = g0lane ? fcw[u] : 0.f;
    const float fcb_l = fcb[0];

    // activation constants per gate lane
    const float m2A = (g == 2) ? 2.885390082f : -1.442695041f;
    const float Aa  = act_lane ? ((g == 2) ? -2.f : 1.f) : 0.f;
    const float Ba  = (act_lane && g == 2) ? 1.f : 0.f;

    // ---- weights: one row of each matrix per lane, stored in AGPRs ----
    // AGPR-class values defined by asm cannot be rematerialized and are
    // outside the VGPR pressure heuristic that spilled rounds 1-3.
    #define DECLW(k) float w1_##k, w2i_##k, w2h_##k;
    FOR51(DECLW)
    #define LOADW(k) { \
        float t_; \
        t_ = act_lane ? Whh1[(size_t)row * H + k] : 0.f; \
        asm volatile("v_accvgpr_write_b32 %0, %1" : "=a"(w1_##k)  : "v"(t_)); \
        t_ = act_lane ? Wih2[(size_t)row * H + k] : 0.f; \
        asm volatile("v_accvgpr_write_b32 %0, %1" : "=a"(w2i_##k) : "v"(t_)); \
        t_ = act_lane ? Whh2[(size_t)row * H + k] : 0.f; \
        asm volatile("v_accvgpr_write_b32 %0, %1" : "=a"(w2h_##k) : "v"(t_)); }
    FOR51(LOADW)

    float c1 = 0.f, c2 = 0.f;                   // cell state (replicated per quad)
    __syncthreads();

    const int TT = T + future;
    for (int t = 0; t < TT; ++t) {
        const int p = t & 1, q = p ^ 1;

        // ---- out(t-1) from fc partials; feedback input in future phase ----
        float xt;
        {
            float o = 0.f;
            if (t > 0) {
                const float4 f = *(const float4*)fcp;
                o = (f.x + f.y) + (f.z + f.w) + fcb_l;
                if (tid == 0) out[(size_t)b * TT + (t - 1)] = o;
            }
            xt = (t < T) ? xld[t] : o;
        }

        // ---- distribute h(t-1): one stride-1 b32 read per vector ----
        const float h1v = h1s[q][l];
        const float h2v = h2s[q][l];

        // ---- phase B: pre1 = b1 + wx1*xt + Whh1.h1 ; hh2 = Whh2.h2 ----
        float a0 = 0.f, a1 = 0.f, a2 = 0.f, a3 = 0.f;
        float d0 = 0.f, d1 = 0.f, d2 = 0.f, d3 = 0.f;
        #define MB(k, j) { \
            float t1_, t2_; \
            asm volatile("v_accvgpr_read_b32 %0, %1" : "=v"(t1_) : "a"(w1_##k)); \
            asm volatile("v_accvgpr_read_b32 %0, %1" : "=v"(t2_) : "a"(w2h_##k)); \
            a##j = fmaf(rl_(h1v, k), t1_, a##j); \
            d##j = fmaf(rl_(h2v, k), t2_, d##j); }
        FOR51_RR(MB)

        const float pre1 = bias1 + fmaf(wx1, xt, (a0 + a1) + (a2 + a3));
        const float hh2  = (d0 + d1) + (d2 + d3);

        float act = act_(pre1, m2A, Aa, Ba);
        {
            const float si = qb_<0x00>(act);
            const float sf = qb_<0x55>(act);
            const float tg = qb_<0xAA>(act);
            const float so = qb_<0xFF>(act);
            c1 = fmaf(sf, c1, si * tg);
            const float h1n = so * tanh_(c1);
            if (g0lane) h1s[p][u] = h1n;
        }
        __syncthreads();                        // barrier 1: h1(t) visible

        // ---- phase C: pre2 = b2 + hh2 + Wih2.h1(t) ----
        const float h1vp = h1s[p][l];
        float e0 = 0.f, e1 = 0.f, e2 = 0.f, e3 = 0.f;
        #define MC(k, j) { \
            float t_; \
            asm volatile("v_accvgpr_read_b32 %0, %1" : "=v"(t_) : "a"(w2i_##k)); \
            e##j = fmaf(rl_(h1vp, k), t_, e##j); }
        FOR51_RR(MC)

        const float pre2 = bias2 + hh2 + ((e0 + e1) + (e2 + e3));
        act = act_(pre2, m2A, Aa, Ba);
        {
            const float si = qb_<0x00>(act);
            const float sf = qb_<0x55>(act);
            const float tg = qb_<0xAA>(act);
            const float so = qb_<0xFF>(act);
            c2 = fmaf(sf, c2, si * tg);
            const float h2n = so * tanh_(c2);
            if (g0lane) h2s[p][u] = h2n;

            // fc partial: sum over units of fcw[u]*h2n(u)  (g==0 lanes carry it)
            float pv = g0lane ? h2n * fcu : 0.f;
            pv += __shfl_xor(pv, 4, 64);
            pv += __shfl_xor(pv, 8, 64);
            pv += __shfl_xor(pv, 16, 64);
            pv += __shfl_xor(pv, 32, 64);
            if (l == 0) fcp[w] = pv;
        }
        __syncthreads();                        // barrier 2: h2(t) + fcp visible
    }

    if (tid == 0) {
        const float4 f = *(const float4*)fcp;
        out[(size_t)b * TT + (TT - 1)] = (f.x + f.y) + (f.z + f.w) + fcb_l;
    }
}

extern "C" void kernel_launch(void* const* d_in, const int* in_sizes, int n_in,
                              void* d_out, int out_size, void* d_ws, size_t ws_size,
                              hipStream_t stream) {
    const float* x    = (const float*)d_in[0];
    const float* Wih1 = (const float*)d_in[1];
    const float* Whh1 = (const float*)d_in[2];
    const float* bih1 = (const float*)d_in[3];
    const float* bhh1 = (const float*)d_in[4];
    const float* Wih2 = (const float*)d_in[5];
    const float* Whh2 = (const float*)d_in[6];
    const float* bih2 = (const float*)d_in[7];
    const float* bhh2 = (const float*)d_in[8];
    const float* fcw  = (const float*)d_in[9];
    const float* fcb  = (const float*)d_in[10];
    float* out = (float*)d_out;

    const int B  = 256;                 // fixed by setup (H=51 hardcoded)
    const int T  = in_sizes[0] / B;     // 2048
    const int TT = out_size / B;        // T + future
    const int future = TT - T;

    const size_t shmem = (size_t)T * sizeof(float);
    hipLaunchKernelGGL(lstm_seq_kernel, dim3(B), dim3(256), shmem, stream,
                       x, Wih1, Whh1, bih1, bhh1, Wih2, Whh2, bih2, bhh2,
                       fcw, fcb, out, T, future);
}

// Round 5
// 2366.738 us; speedup vs baseline: 1.3849x; 1.3849x over previous
//
#include <hip/hip_runtime.h>

#define H 51

__device__ __forceinline__ float rl_(float v, int lane) {
    return __builtin_bit_cast(float, __builtin_amdgcn_readlane(__builtin_bit_cast(int, v), lane));
}
template<int CTRL>
__device__ __forceinline__ float qb_(float v) {   // quad_perm broadcast (DPP, VALU pipe)
    return __builtin_bit_cast(float, __builtin_amdgcn_update_dpp(
        0, __builtin_bit_cast(int, v), CTRL, 0xf, 0xf, true));
}

// act = A * rcp(1 + exp2(m2*x)) + B   (sigmoid: m2=-log2e,A=1,B=0 ; tanh: m2=2log2e,A=-2,B=1)
__device__ __forceinline__ float act_(float x, float m2, float A, float B) {
    const float e = __builtin_amdgcn_exp2f(m2 * x);
    const float r = __builtin_amdgcn_rcpf(1.f + e);
    return fmaf(A, r, B);
}
__device__ __forceinline__ float tanh_(float c) {
    const float e = __builtin_amdgcn_exp2f(2.885390082f * c);
    const float r = __builtin_amdgcn_rcpf(1.f + e);
    return fmaf(-2.f, r, 1.f);
}

// 51-MAC dot of lane-distributed h (via readlane) against per-lane row wt[]
__device__ __forceinline__ float dot51_(const float* wt, float hv) {
    float a0 = 0.f, a1 = 0.f, a2 = 0.f, a3 = 0.f;
    #pragma unroll
    for (int k = 0; k < 48; k += 4) {
        a0 = fmaf(rl_(hv, k + 0), wt[k + 0], a0);
        a1 = fmaf(rl_(hv, k + 1), wt[k + 1], a1);
        a2 = fmaf(rl_(hv, k + 2), wt[k + 2], a2);
        a3 = fmaf(rl_(hv, k + 3), wt[k + 3], a3);
    }
    a0 = fmaf(rl_(hv, 48), wt[48], a0);
    a1 = fmaf(rl_(hv, 49), wt[49], a1);
    a2 = fmaf(rl_(hv, 50), wt[50], a2);
    return (a0 + a1) + (a2 + a3);
}

__global__ __launch_bounds__(768, 1)
void lstm_seq_kernel(const float* __restrict__ x,
                     const float* __restrict__ Wih1, const float* __restrict__ Whh1,
                     const float* __restrict__ bih1, const float* __restrict__ bhh1,
                     const float* __restrict__ Wih2, const float* __restrict__ Whh2,
                     const float* __restrict__ bih2, const float* __restrict__ bhh2,
                     const float* __restrict__ fcw, const float* __restrict__ fcb,
                     float* __restrict__ out, int T, int future)
{
    const int b   = blockIdx.x;
    const int tid = threadIdx.x;
    const int l   = tid & 63;          // lane
    const int w   = tid >> 6;          // wave 0..11
    const int grp = w >> 2;            // 0: Whh1+act1+c1 | 1: Whh2 partial | 2: Wih2+act2+c2+fc
    const int j   = w & 3;             // wave within group
    const int uq  = l >> 2;            // unit-within-wave 0..15 (13 valid)
    const int g   = l & 3;             // gate 0:i 1:f 2:g 3:o
    const int u   = 13 * j + uq;       // unit 0..50 (wave j=3 has 12 valid)
    const bool act_lane = (uq < 13) && (u < H);
    const bool g0lane   = act_lane && (g == 0);
    const int row = act_lane ? (g * H + u) : 0;

    extern __shared__ float xld[];              // [T] this batch row of x
    __shared__ float h1s[2][64];                // double-buffered h1 (pad zeros)
    __shared__ float h2s[2][64];
    __shared__ float hh2buf[208];               // Whh2.h2 partial, idx = 52*j + l
    __shared__ __align__(16) float fcp[4];      // per-wave fc partial sums

    for (int i = tid; i < T; i += 768) xld[i] = x[(size_t)b * T + i];
    if (tid < 64) { h1s[0][tid] = 0.f; h1s[1][tid] = 0.f;
                    h2s[0][tid] = 0.f; h2s[1][tid] = 0.f; }
    if (tid < 4) fcp[tid] = 0.f;

    // per-lane weight row: ONE matrix row (51 floats) per lane — small enough
    // that the register allocator keeps it resident (rounds 1-4 post-mortem).
    const float* Wm = (grp == 0) ? Whh1 : ((grp == 1) ? Whh2 : Wih2);
    float wt[H];
    #pragma unroll
    for (int k = 0; k < H; ++k)
        wt[k] = act_lane ? Wm[(size_t)row * H + k] : 0.f;

    // per-row constants
    const float wx1   = (grp == 0 && act_lane) ? Wih1[row] : 0.f;
    const float bias1 = (grp == 0 && act_lane) ? (bih1[row] + bhh1[row]) : 0.f;
    const float bias2 = (grp == 2 && act_lane) ? (bih2[row] + bhh2[row]) : 0.f;
    const float fcu   = (grp == 2 && g0lane) ? fcw[u] : 0.f;
    const float fcb_l = fcb[0];

    // activation constants per gate lane (grp 0 and 2)
    const float m2A = (g == 2) ? 2.885390082f : -1.442695041f;
    const float Aa  = act_lane ? ((g == 2) ? -2.f : 1.f) : 0.f;
    const float Ba  = (act_lane && g == 2) ? 1.f : 0.f;

    float cc = 0.f;                    // c1 (grp0) / c2 (grp2), quad-replicated
    __syncthreads();

    const int TT = T + future;
    for (int t = 0; t < TT; ++t) {
        const int p = t & 1, q = p ^ 1;

        // ---- out(t-1) from fc partials (all threads compute o; tid0 stores) ----
        float o = 0.f;
        if (t > 0) {
            const float4 f = *(const float4*)fcp;
            o = (f.x + f.y) + (f.z + f.w) + fcb_l;
            if (tid == 0) out[(size_t)b * TT + (t - 1)] = o;
        }

        // ================= phase B =================
        if (grp == 0) {
            // full layer 1: pre1 -> gates (DPP quad) -> c1 -> h1(t)
            const float xt = (t < T) ? xld[t] : o;
            const float hv = h1s[q][l];
            const float pre1 = bias1 + fmaf(wx1, xt, dot51_(wt, hv));
            const float a = act_(pre1, m2A, Aa, Ba);
            const float si = qb_<0x00>(a);
            const float sf = qb_<0x55>(a);
            const float tg = qb_<0xAA>(a);
            const float so = qb_<0xFF>(a);
            cc = fmaf(sf, cc, si * tg);
            const float h1n = so * tanh_(cc);
            if (g0lane) h1s[p][u] = h1n;
        } else if (grp == 1) {
            // hh2 = Whh2[row,:] . h2(t-1)
            const float hv = h2s[q][l];
            const float hh2 = dot51_(wt, hv);
            if (act_lane) hh2buf[52 * j + l] = hh2;
        }
        __syncthreads();                       // barrier 1: h1(t), hh2buf visible

        // ================= phase C =================
        if (grp == 2) {
            const float hv = h1s[p][l];
            const float dot = dot51_(wt, hv);
            const float hh2 = act_lane ? hh2buf[52 * j + l] : 0.f;
            const float pre2 = bias2 + hh2 + dot;
            const float a = act_(pre2, m2A, Aa, Ba);
            const float si = qb_<0x00>(a);
            const float sf = qb_<0x55>(a);
            const float tg = qb_<0xAA>(a);
            const float so = qb_<0xFF>(a);
            cc = fmaf(sf, cc, si * tg);
            const float h2n = so * tanh_(cc);
            if (g0lane) h2s[p][u] = h2n;

            // fc partial for this wave's 13 units
            float pv = g0lane ? h2n * fcu : 0.f;
            pv += __shfl_xor(pv, 4, 64);
            pv += __shfl_xor(pv, 8, 64);
            pv += __shfl_xor(pv, 16, 64);
            pv += __shfl_xor(pv, 32, 64);
            if (l == 0) fcp[j] = pv;
        }
        __syncthreads();                       // barrier 2: h2(t), fcp visible
    }

    if (tid == 0) {
        const float4 f = *(const float4*)fcp;
        out[(size_t)b * TT + (TT - 1)] = (f.x + f.y) + (f.z + f.w) + fcb_l;
    }
}

extern "C" void kernel_launch(void* const* d_in, const int* in_sizes, int n_in,
                              void* d_out, int out_size, void* d_ws, size_t ws_size,
                              hipStream_t stream) {
    const float* x    = (const float*)d_in[0];
    const float* Wih1 = (const float*)d_in[1];
    const float* Whh1 = (const float*)d_in[2];
    const float* bih1 = (const float*)d_in[3];
    const float* bhh1 = (const float*)d_in[4];
    const float* Wih2 = (const float*)d_in[5];
    const float* Whh2 = (const float*)d_in[6];
    const float* bih2 = (const float*)d_in[7];
    const float* bhh2 = (const float*)d_in[8];
    const float* fcw  = (const float*)d_in[9];
    const float* fcb  = (const float*)d_in[10];
    float* out = (float*)d_out;

    const int B  = 256;                 // fixed by setup (H=51 hardcoded)
    const int T  = in_sizes[0] / B;     // 2048
    const int TT = out_size / B;        // T + future
    const int future = TT - T;

    const size_t shmem = (size_t)T * sizeof(float);
    hipLaunchKernelGGL(lstm_seq_kernel, dim3(B), dim3(768), shmem, stream,
                       x, Wih1, Whh1, bih1, bhh1, Wih2, Whh2, bih2, bhh2,
                       fcw, fcb, out, T, future);
}

// Round 6
// 2292.473 us; speedup vs baseline: 1.4297x; 1.0324x over previous
//
#include <hip/hip_runtime.h>

#define H 51

__device__ __forceinline__ float rl_(float v, int lane) {
    return __builtin_bit_cast(float, __builtin_amdgcn_readlane(__builtin_bit_cast(int, v), lane));
}
template<int CTRL>
__device__ __forceinline__ float qb_(float v) {   // quad_perm broadcast (DPP, VALU pipe)
    return __builtin_bit_cast(float, __builtin_amdgcn_update_dpp(
        0, __builtin_bit_cast(int, v), CTRL, 0xf, 0xf, true));
}

// act = A * rcp(1 + exp2(m2*x)) + B   (sigmoid: m2=-log2e,A=1,B=0 ; tanh: m2=2log2e,A=-2,B=1)
__device__ __forceinline__ float act_(float x, float m2, float A, float B) {
    const float e = __builtin_amdgcn_exp2f(m2 * x);
    const float r = __builtin_amdgcn_rcpf(1.f + e);
    return fmaf(A, r, B);
}
__device__ __forceinline__ float tanh_(float c) {
    const float e = __builtin_amdgcn_exp2f(2.885390082f * c);
    const float r = __builtin_amdgcn_rcpf(1.f + e);
    return fmaf(-2.f, r, 1.f);
}

// ---- apply M(k) for k = 0..50 ----
#define FOR51(M) \
 M(0) M(1) M(2) M(3) M(4) M(5) M(6) M(7) M(8) M(9) \
 M(10) M(11) M(12) M(13) M(14) M(15) M(16) M(17) M(18) M(19) \
 M(20) M(21) M(22) M(23) M(24) M(25) M(26) M(27) M(28) M(29) \
 M(30) M(31) M(32) M(33) M(34) M(35) M(36) M(37) M(38) M(39) \
 M(40) M(41) M(42) M(43) M(44) M(45) M(46) M(47) M(48) M(49) M(50)

// ---- apply M(k, k%4) for k = 0..50 (round-robin accumulators) ----
#define FOR51_RR(M) \
 M(0,0) M(1,1) M(2,2) M(3,3) M(4,0) M(5,1) M(6,2) M(7,3) \
 M(8,0) M(9,1) M(10,2) M(11,3) M(12,0) M(13,1) M(14,2) M(15,3) \
 M(16,0) M(17,1) M(18,2) M(19,3) M(20,0) M(21,1) M(22,2) M(23,3) \
 M(24,0) M(25,1) M(26,2) M(27,3) M(28,0) M(29,1) M(30,2) M(31,3) \
 M(32,0) M(33,1) M(34,2) M(35,3) M(36,0) M(37,1) M(38,2) M(39,3) \
 M(40,0) M(41,1) M(42,2) M(43,3) M(44,0) M(45,1) M(46,2) M(47,3) \
 M(48,0) M(49,1) M(50,2)

__global__ __launch_bounds__(768, 1)
void lstm_seq_kernel(const float* __restrict__ x,
                     const float* __restrict__ Wih1, const float* __restrict__ Whh1,
                     const float* __restrict__ bih1, const float* __restrict__ bhh1,
                     const float* __restrict__ Wih2, const float* __restrict__ Whh2,
                     const float* __restrict__ bih2, const float* __restrict__ bhh2,
                     const float* __restrict__ fcw, const float* __restrict__ fcb,
                     float* __restrict__ out, int T, int future)
{
    const int b   = blockIdx.x;
    const int tid = threadIdx.x;
    const int l   = tid & 63;          // lane
    const int w   = tid >> 6;          // wave 0..11
    const int grp = w >> 2;            // 0: Whh1+act1+c1 | 1: Whh2 partial | 2: Wih2+act2+c2+fc
    const int j   = w & 3;             // wave within group
    const int uq  = l >> 2;            // unit-within-wave 0..15 (13 valid)
    const int g   = l & 3;             // gate 0:i 1:f 2:g 3:o
    const int u   = 13 * j + uq;       // unit 0..50 (wave j=3 has 12 valid)
    const bool act_lane = (uq < 13) && (u < H);
    const bool g0lane   = act_lane && (g == 0);
    const int row = act_lane ? (g * H + u) : 0;     // clamped: inactive lanes read row 0

    extern __shared__ float xld[];              // [T] this batch row of x
    __shared__ float h1s[2][64];                // double-buffered h1 (pad zeros)
    __shared__ float h2s[2][64];
    __shared__ float hh2buf[220];               // Whh2.h2 partial, idx = 52*j + l
    __shared__ __align__(16) float fcp[4];      // per-wave fc partial sums

    for (int i = tid; i < T; i += 768) xld[i] = x[(size_t)b * T + i];
    if (tid < 64) { h1s[0][tid] = 0.f; h1s[1][tid] = 0.f;
                    h2s[0][tid] = 0.f; h2s[1][tid] = 0.f; }
    if (tid < 4) fcp[tid] = 0.f;

    // per-lane weight row as 51 NAMED scalars (no array -> no SROA scratch,
    // no runtime index; ~85 live regs, inside the allocator's keep zone).
    const float* Wm = (grp == 0) ? Whh1 : ((grp == 1) ? Whh2 : Wih2);
    const size_t rb = (size_t)row * H;
    #define DECLW(k) float wt_##k;
    FOR51(DECLW)
    #define LOADW(k) wt_##k = Wm[rb + k];
    FOR51(LOADW)

    // per-row constants
    const float wx1   = (grp == 0 && act_lane) ? Wih1[row] : 0.f;
    const float bias1 = (grp == 0 && act_lane) ? (bih1[row] + bhh1[row]) : 0.f;
    const float bias2 = (grp == 2 && act_lane) ? (bih2[row] + bhh2[row]) : 0.f;
    const float fcu   = g0lane ? fcw[(grp == 2) ? u : 0] * (grp == 2 ? 1.f : 0.f) : 0.f;
    const float fcb_l = fcb[0];

    // activation constants per gate lane (grp 0 and 2)
    const float m2A = (g == 2) ? 2.885390082f : -1.442695041f;
    const float Aa  = act_lane ? ((g == 2) ? -2.f : 1.f) : 0.f;
    const float Ba  = (act_lane && g == 2) ? 1.f : 0.f;

    float cc = 0.f;                    // c1 (grp0) / c2 (grp2), quad-replicated
    __syncthreads();

    const int TT = T + future;
    for (int t = 0; t < TT; ++t) {
        const int p = t & 1, q = p ^ 1;

        // ---- out(t-1) from fc partials (all threads compute o; tid0 stores) ----
        float o = 0.f;
        if (t > 0) {
            const float4 f = *(const float4*)fcp;
            o = (f.x + f.y) + (f.z + f.w) + fcb_l;
            if (tid == 0) out[(size_t)b * TT + (t - 1)] = o;
        }

        // ================= phase B =================
        if (grp == 0) {
            // full layer 1: pre1 -> gates (DPP quad) -> c1 -> h1(t)
            const float xt = (t < T) ? xld[t] : o;
            const float hv = h1s[q][l];
            float a0 = 0.f, a1 = 0.f, a2 = 0.f, a3 = 0.f;
            #define MACB(k, jj) a##jj = fmaf(rl_(hv, k), wt_##k, a##jj);
            FOR51_RR(MACB)
            const float pre1 = bias1 + fmaf(wx1, xt, (a0 + a1) + (a2 + a3));
            const float a = act_(pre1, m2A, Aa, Ba);
            const float si = qb_<0x00>(a);
            const float sf = qb_<0x55>(a);
            const float tg = qb_<0xAA>(a);
            const float so = qb_<0xFF>(a);
            cc = fmaf(sf, cc, si * tg);
            const float h1n = so * tanh_(cc);
            if (g0lane) h1s[p][u] = h1n;
        } else if (grp == 1) {
            // hh2 = Whh2[row,:] . h2(t-1)
            const float hv = h2s[q][l];
            float a0 = 0.f, a1 = 0.f, a2 = 0.f, a3 = 0.f;
            FOR51_RR(MACB)
            if (act_lane) hh2buf[52 * j + l] = (a0 + a1) + (a2 + a3);
        }
        __syncthreads();                       // barrier 1: h1(t), hh2buf visible

        // ================= phase C =================
        if (grp == 2) {
            const float hv = h1s[p][l];
            float a0 = 0.f, a1 = 0.f, a2 = 0.f, a3 = 0.f;
            FOR51_RR(MACB)
            const float hh2 = act_lane ? hh2buf[52 * j + l] : 0.f;
            const float pre2 = bias2 + hh2 + ((a0 + a1) + (a2 + a3));
            const float a = act_(pre2, m2A, Aa, Ba);
            const float si = qb_<0x00>(a);
            const float sf = qb_<0x55>(a);
            const float tg = qb_<0xAA>(a);
            const float so = qb_<0xFF>(a);
            cc = fmaf(sf, cc, si * tg);
            const float h2n = so * tanh_(cc);
            if (g0lane) h2s[p][u] = h2n;

            // fc partial for this wave's 13 units
            float pv = g0lane ? h2n * fcu : 0.f;
            pv += __shfl_xor(pv, 4, 64);
            pv += __shfl_xor(pv, 8, 64);
            pv += __shfl_xor(pv, 16, 64);
            pv += __shfl_xor(pv, 32, 64);
            if (l == 0) fcp[j] = pv;
        }
        __syncthreads();                       // barrier 2: h2(t), fcp visible
    }

    if (tid == 0) {
        const float4 f = *(const float4*)fcp;
        out[(size_t)b * TT + (TT - 1)] = (f.x + f.y) + (f.z + f.w) + fcb_l;
    }
}

extern "C" void kernel_launch(void* const* d_in, const int* in_sizes, int n_in,
                              void* d_out, int out_size, void* d_ws, size_t ws_size,
                              hipStream_t stream) {
    const float* x    = (const float*)d_in[0];
    const float* Wih1 = (const float*)d_in[1];
    const float* Whh1 = (const float*)d_in[2];
    const float* bih1 = (const float*)d_in[3];
    const float* bhh1 = (const float*)d_in[4];
    const float* Wih2 = (const float*)d_in[5];
    const float* Whh2 = (const float*)d_in[6];
    const float* bih2 = (const float*)d_in[7];
    const float* bhh2 = (const float*)d_in[8];
    const float* fcw  = (const float*)d_in[9];
    const float* fcb  = (const float*)d_in[10];
    float* out = (float*)d_out;

    const int B  = 256;                 // fixed by setup (H=51 hardcoded)
    const int T  = in_sizes[0] / B;     // 2048
    const int TT = out_size / B;        // T + future
    const int future = TT - T;

    const size_t shmem = (size_t)T * sizeof(float);
    hipLaunchKernelGGL(lstm_seq_kernel, dim3(B), dim3(768), shmem, stream,
                       x, Wih1, Whh1, bih1, bhh1, Wih2, Whh2, bih2, bhh2,
                       fcw, fcb, out, T, future);
}